// Round 1
// baseline (654.837 us; speedup 1.0000x reference)
//
#include <hip/hip_runtime.h>

// out[b,i,j] = W[words[b,i], words[b,j]]  (+ root[words[b,i]] when i==j)
// B=8, N=2048, V=10000. Output fp32, 128 MiB.
//
// Strategy R0: one block per output row (b,i). wi is block-uniform (scalar
// load). Each thread gathers 4 consecutive j (int4 word load -> 4 scattered
// 4B reads in the same 40KB W row -> float4 coalesced store). L1 caches the
// W row across the block's 2048 gathers.

#define VOCAB 10000
#define BATCH 8
#define SEQ   2048

__global__ __launch_bounds__(256) void gather2d_kernel(
    const int*   __restrict__ words,
    const float* __restrict__ W,
    const float* __restrict__ root,
    float*       __restrict__ out)
{
    const int i = blockIdx.x;          // output row within batch
    const int b = blockIdx.y;          // batch
    const int wi = words[b * SEQ + i]; // block-uniform -> s_load
    const float rs = root[wi];

    const float* __restrict__ Wrow = W + (size_t)wi * VOCAB;
    const int*   __restrict__ wrow = words + b * SEQ;
    float*       __restrict__ orow = out + ((size_t)b * SEQ + i) * SEQ;

    // SEQ / (256 threads * 4 per thread) = 2 iterations
    #pragma unroll
    for (int k = 0; k < 2; ++k) {
        const int j = (threadIdx.x + k * 256) * 4;
        const int4 wj = *(const int4*)(wrow + j);
        float4 v;
        v.x = Wrow[wj.x];
        v.y = Wrow[wj.y];
        v.z = Wrow[wj.z];
        v.w = Wrow[wj.w];
        // diagonal add: j..j+3 covers i for exactly one thread/iter
        const unsigned d = (unsigned)(i - j);
        if (d < 4u) ((float*)&v)[d] += rs;
        *(float4*)(orow + j) = v;
    }
}

extern "C" void kernel_launch(void* const* d_in, const int* in_sizes, int n_in,
                              void* d_out, int out_size, void* d_ws, size_t ws_size,
                              hipStream_t stream)
{
    const int*   words = (const int*)d_in[0];
    const float* W     = (const float*)d_in[1];
    const float* root  = (const float*)d_in[2];
    float*       out   = (float*)d_out;

    dim3 grid(SEQ, BATCH);
    gather2d_kernel<<<grid, 256, 0, stream>>>(words, W, root, out);
}

// Round 2
// 582.306 us; speedup vs baseline: 1.1246x; 1.1246x over previous
//
#include <hip/hip_runtime.h>

// out[b,i,j] = W[words[b,i], words[b,j]]  (+ root[words[b,i]] when i==j)
// B=8, N=2048, V=10000. Output fp32, 128 MiB.
//
// R2: per-block LDS staging of the single W row this block gathers from.
// R1 was scattered-load issue-bound (hbm 31%, VALU 2%): 33.5M random 4B
// global gathers serialize in the TA/TCP pipe. Now: coalesced
// global_load_lds dwordx4 stages the 40KB row -> random gather moves to LDS
// (ds_read_b32, conflicts cheap), store stays coalesced float4.
// LDS 40KB/block -> 4 blocks/CU x 512 thr = 32 waves/CU.

#define VOCAB 10000
#define BATCH 8
#define SEQ   2048
#define TPB   512

__global__ __launch_bounds__(TPB) void gather2d_lds_kernel(
    const int*   __restrict__ words,
    const float* __restrict__ W,
    const float* __restrict__ root,
    float*       __restrict__ out)
{
    __shared__ float row[VOCAB];   // 40000 B

    const int i = blockIdx.x;          // output row within batch
    const int b = blockIdx.y;          // batch
    const int wi = words[b * SEQ + i]; // block-uniform -> scalar load
    const float rs = root[wi];

    const float* __restrict__ Wrow = W + (size_t)wi * VOCAB;
    const int*   __restrict__ wrow = words + b * SEQ;
    float*       __restrict__ orow = out + ((size_t)b * SEQ + i) * SEQ;

    // Stage Wrow -> LDS: 2500 float4 chunks (40000 B, 16B-aligned since
    // VOCAB*4 = 40000 = 2500*16). global_load_lds: lane dest = uniform
    // base + lane*16, which idx = it*TPB + tid satisfies.
    #pragma unroll
    for (int it = 0; it < 5; ++it) {
        const int idx = it * TPB + threadIdx.x;   // float4 index
        if (idx < VOCAB / 4) {
            __builtin_amdgcn_global_load_lds(
                (const __attribute__((address_space(1))) void*)(Wrow + idx * 4),
                (__attribute__((address_space(3))) void*)(row + idx * 4),
                16, 0, 0);
        }
    }
    __syncthreads();

    // Gather: each thread one float4 of output. SEQ = TPB*4 exactly.
    const int j = threadIdx.x * 4;
    const int4 wj = *(const int4*)(wrow + j);
    float4 v;
    v.x = row[wj.x];
    v.y = row[wj.y];
    v.z = row[wj.z];
    v.w = row[wj.w];
    const unsigned d = (unsigned)(i - j);
    if (d < 4u) ((float*)&v)[d] += rs;
    *(float4*)(orow + j) = v;
}

extern "C" void kernel_launch(void* const* d_in, const int* in_sizes, int n_in,
                              void* d_out, int out_size, void* d_ws, size_t ws_size,
                              hipStream_t stream)
{
    const int*   words = (const int*)d_in[0];
    const float* W     = (const float*)d_in[1];
    const float* root  = (const float*)d_in[2];
    float*       out   = (float*)d_out;

    dim3 grid(SEQ, BATCH);
    gather2d_lds_kernel<<<grid, TPB, 0, stream>>>(words, W, root, out);
}